// Round 5
// baseline (1477.420 us; speedup 1.0000x reference)
//
#include <hip/hip_runtime.h>

typedef unsigned short u16;
typedef __attribute__((ext_vector_type(8))) short bf16x8;
typedef __attribute__((ext_vector_type(4))) float f32x4;
typedef __attribute__((ext_vector_type(4))) unsigned int u32x4;

__device__ __forceinline__ float bf2f(u16 u) {
  unsigned int x = ((unsigned int)u) << 16;
  return __builtin_bit_cast(float, x);
}
__device__ __forceinline__ u16 f2bf(float f) {
  unsigned int x = __builtin_bit_cast(unsigned int, f);
  x += 0x7fff + ((x >> 16) & 1);   // RNE
  return (u16)(x >> 16);
}
// 2^x via v_exp_f32 (native exp2 on gfx950).
__device__ __forceinline__ float exp2f_fast(float x) {
  return __builtin_amdgcn_exp2f(x);
}
__device__ __forceinline__ void gload16(const u16* g, u16* l) {
  __builtin_amdgcn_global_load_lds((const __attribute__((address_space(1))) void*)g,
                                   (__attribute__((address_space(3))) void*)l, 16, 0, 0);
}
// Direct global->VGPR 16B load, saddr + 32-bit voffset. Asynchronous: the
// result VGPRs are NOT valid until a manual s_waitcnt vmcnt covers this load.
__device__ __forceinline__ bf16x8 gload_v(const u16* sbase, unsigned voff_bytes) {
  u32x4 r;
  asm volatile("global_load_dwordx4 %0, %1, %2"
               : "=v"(r) : "v"(voff_bytes), "s"(sbase) : "memory");
  return __builtin_bit_cast(bf16x8, r);
}
__device__ __forceinline__ unsigned cvt_pk_bf16(float lo, float hi) {
  unsigned r;
  asm("v_cvt_pk_bf16_f32 %0, %1, %2" : "=v"(r) : "v"(lo), "v"(hi));
  return r;
}
#define MFMA16(a, b, c) __builtin_amdgcn_mfma_f32_16x16x32_bf16(a, b, c, 0, 0, 0)

// ---------------------------------------------------------------------------
// fp32 -> bf16 elementwise convert. grid n4/256, block 256 (n4 = n/4).
// ---------------------------------------------------------------------------
__global__ __launch_bounds__(256) void convert_k(const float* __restrict__ in,
                                                 u16* __restrict__ out, int n4) {
  const int i = blockIdx.x * 256 + threadIdx.x;
  if (i < n4) {
    float4 f = ((const float4*)in)[i];
    ushort4 v;
    v.x = f2bf(f.x); v.y = f2bf(f.y); v.z = f2bf(f.z); v.w = f2bf(f.w);
    ((ushort4*)out)[i] = v;
  }
}

// ---------------------------------------------------------------------------
// Transpose+convert: in fp32 (R x C) row-major -> out bf16 (Cpad x R) row-major;
// out rows >= C zeroed. R mult of 64, C mult of 4. grid (R/64, Cpad/64), blk 256.
// ---------------------------------------------------------------------------
__global__ __launch_bounds__(256) void transpose_k(const float* __restrict__ in,
                                                   u16* __restrict__ out,
                                                   int R, int C) {
  __shared__ u16 t[64][65];
  const int r0 = blockIdx.x * 64, c0 = blockIdx.y * 64;
  const int x = threadIdx.x & 15, y = threadIdx.x >> 4;
  if (c0 < C) {
#pragma unroll
    for (int i = 0; i < 4; i++) {
      const float* g = in + (size_t)(r0 + y + 16 * i) * C + c0 + 4 * x;
      float4 v = *(const float4*)g;
      t[y + 16 * i][4 * x + 0] = f2bf(v.x);
      t[y + 16 * i][4 * x + 1] = f2bf(v.y);
      t[y + 16 * i][4 * x + 2] = f2bf(v.z);
      t[y + 16 * i][4 * x + 3] = f2bf(v.w);
    }
    __syncthreads();
#pragma unroll
    for (int i = 0; i < 4; i++) {
      const int cc = y + 16 * i;
      ushort4 v;
      v.x = t[4 * x + 0][cc];
      v.y = t[4 * x + 1][cc];
      v.z = t[4 * x + 2][cc];
      v.w = t[4 * x + 3][cc];
      *(ushort4*)(out + (size_t)(c0 + cc) * R + r0 + 4 * x) = v;
    }
  } else {
    ushort4 z = {0, 0, 0, 0};
#pragma unroll
    for (int i = 0; i < 4; i++)
      *(ushort4*)(out + (size_t)(c0 + y + 16 * i) * R + r0 + 4 * x) = z;
  }
}

// ---------------------------------------------------------------------------
// GEMM: C(M x N) = A(M x K) * Bt(N x K)^T, bf16 in, fp32 accum.
// m97 structure: 128x128 tile, BK=32, global_load_lds(16B), 16x16x32 MFMA.
// MODE 0: bf16 row-major C, stride ldc.
// MODE 1: kv split epilogue: col n -> (h = n>>8, c = n&255);
//         c<128 -> knope[row*5120 + h*128 + c]  (bf16)
//         else  -> vT[((b*40+h)*128 + (c-128))*2048 + s]  (bf16; b=row>>11)
// MODE 2: fp32 row-major C, stride ldc.
// grid = (M/128, N/128), block 256.
// ---------------------------------------------------------------------------
template <int MODE>
__global__ __launch_bounds__(256) void gemm_bt(const u16* __restrict__ A, int lda,
                                               const u16* __restrict__ Bt, int ldb,
                                               void* __restrict__ Cp, int ldc,
                                               u16* __restrict__ C1, int K) {
  __shared__ u16 lA[128 * 32];
  __shared__ u16 lB[128 * 32];
  const int tid = threadIdx.x;
  const int m0 = blockIdx.x * 128, n0 = blockIdx.y * 128;
  const int w = tid >> 6, lane = tid & 63, r = lane & 15, quad = lane >> 4;
  const int wr = (w >> 1) * 64, wc = (w & 1) * 64;

  f32x4 acc[4][4];
#pragma unroll
  for (int i = 0; i < 4; i++)
#pragma unroll
    for (int j = 0; j < 4; j++) acc[i][j] = (f32x4){0.f, 0.f, 0.f, 0.f};

  const int r_a = tid >> 2;
  const int c_a = (tid & 3) * 8;
  const u16* gA = A + (size_t)(m0 + r_a) * lda + c_a;
  const u16* gB = Bt + (size_t)(n0 + r_a) * ldb + c_a;
  u16* lAb = lA + (tid & 192) * 8;
  u16* lBb = lB + (tid & 192) * 8;

  for (int k0 = 0; k0 < K; k0 += 32) {
    __syncthreads();
    gload16(gA + k0, lAb);
    gload16(gA + (size_t)64 * lda + k0, lAb + 2048);
    gload16(gB + k0, lBb);
    gload16(gB + (size_t)64 * ldb + k0, lBb + 2048);
    __syncthreads();
    bf16x8 af[4], bf[4];
#pragma unroll
    for (int i = 0; i < 4; i++) af[i] = *(const bf16x8*)&lA[(wr + i * 16 + r) * 32 + quad * 8];
#pragma unroll
    for (int j = 0; j < 4; j++) bf[j] = *(const bf16x8*)&lB[(wc + j * 16 + r) * 32 + quad * 8];
#pragma unroll
    for (int i = 0; i < 4; i++)
#pragma unroll
      for (int j = 0; j < 4; j++) acc[i][j] = MFMA16(af[i], bf[j], acc[i][j]);
  }

#pragma unroll
  for (int i = 0; i < 4; i++) {
#pragma unroll
    for (int j = 0; j < 4; j++) {
#pragma unroll
      for (int reg = 0; reg < 4; reg++) {
        const int row = m0 + wr + i * 16 + quad * 4 + reg;
        const int col = n0 + wc + j * 16 + r;
        const float fv = acc[i][j][reg];
        if (MODE == 0) {
          ((u16*)Cp)[(size_t)row * ldc + col] = f2bf(fv);
        } else if (MODE == 2) {
          ((float*)Cp)[(size_t)row * ldc + col] = fv;
        } else {
          const int hh = col >> 8, cc = col & 255;
          if (cc < 128) {
            ((u16*)Cp)[(size_t)row * 5120 + hh * 128 + cc] = f2bf(fv);
          } else {
            const int bb = row >> 11, ss = row & 2047;
            C1[(((size_t)(bb * 40 + hh)) * 128 + (cc - 128)) * 2048 + ss] = f2bf(fv);
          }
        }
      }
    }
  }
}

// ---------------------------------------------------------------------------
// RMSNorm in-place on aB (4096 x 2176 bf16): seg 0 = cols [0,1536) w/ q_ln_w,
// seg 1 = cols [1536,2048) w/ kv_ln_w (both fp32). grid (4096, 2), block 256.
// ---------------------------------------------------------------------------
__global__ __launch_bounds__(256) void rmsnorm_k(u16* __restrict__ a,
                                                 const float* __restrict__ qw,
                                                 const float* __restrict__ kvw) {
  const int row = blockIdx.x, seg = blockIdx.y;
  const int off = seg ? 1536 : 0;
  const int width = seg ? 512 : 1536;
  const float* wp = seg ? kvw : qw;
  u16* p = a + (size_t)row * 2176 + off;
  const int tid = threadIdx.x;
  float ss = 0.f;
  for (int i = tid; i < width; i += 256) {
    float v = bf2f(p[i]);
    ss += v * v;
  }
#pragma unroll
  for (int o = 32; o >= 1; o >>= 1) ss += __shfl_xor(ss, o, 64);
  __shared__ float red[4];
  if ((tid & 63) == 0) red[tid >> 6] = ss;
  __syncthreads();
  const float tot = red[0] + red[1] + red[2] + red[3];
  const float rs = rsqrtf(tot / (float)width + 1e-6f);
  for (int i = tid; i < width; i += 256) p[i] = f2bf(bf2f(p[i]) * rs * wp[i]);
}

// ---------------------------------------------------------------------------
// RoPE in-place: k_pe at aB[row, 2048:2112]; q_pe at qB[row, h*192+128:+192).
// grid 4096, block 256.
// ---------------------------------------------------------------------------
__global__ __launch_bounds__(256) void rope_k(u16* __restrict__ a, u16* __restrict__ q) {
  const int row = blockIdx.x;
  const int s = row & 2047;
  const int tid = threadIdx.x;
  __shared__ float cs[32], sn[32];
  if (tid < 32) {
    float inv = powf(10000.f, -(float)tid * (1.f / 32.f));
    float ang = (float)s * inv;
    cs[tid] = cosf(ang);
    sn[tid] = sinf(ang);
  }
  __syncthreads();
  if (tid < 32) {
    u16* p = a + (size_t)row * 2176 + 2048;
    float t1 = bf2f(p[tid]), t2 = bf2f(p[tid + 32]);
    p[tid] = f2bf(t1 * cs[tid] - t2 * sn[tid]);
    p[tid + 32] = f2bf(t2 * cs[tid] + t1 * sn[tid]);
  }
  for (int item = tid; item < 1280; item += 256) {
    const int hh = item >> 5, i = item & 31;
    u16* p = q + (size_t)row * 7680 + hh * 192 + 128;
    float t1 = bf2f(p[i]), t2 = bf2f(p[i + 32]);
    p[i] = f2bf(t1 * cs[i] - t2 * sn[i]);
    p[i + 32] = f2bf(t2 * cs[i] + t1 * sn[i]);
  }
}

// ---------------------------------------------------------------------------
// Flash causal attention, v3b (round-3 design + async-register-safety fixes):
//  - K double-buffered in LDS (gload_lds), counted vmcnt (T4).
//  - V loaded DIRECTLY global->VGPR via asm global_load_dwordx4 (L2-resident
//    after T1 head-clustering); no V LDS staging or LDS reads.
//  - Row-sum l via PV MFMA against an all-ones B-fragment.
//  - Scale folded into exp2 argument (v_exp_f32 is native 2^x).
//  - P f32->bf16 via v_cvt_pk_bf16_f32.
// SAFETY: every asm V-load is covered by an UNCONDITIONAL vmcnt wait each
// iteration (all control paths), plus vmcnt(0) after the loop. No forced
// occupancy bound (a VGPR cap could spill asm-pending regs = corruption).
//
// Per-wave vmcnt FIFO per iter: [K(kt):3][V(kt):8][K(kt+1):3]
//   after stage:  vmcnt(11) -> K(kt) landed, V+K(kt+1) in flight; s_barrier
//   mid-iter:     vmcnt(3)  -> V landed (unconditional), K(kt+1) in flight
//   end:          lgkmcnt(0); s_barrier (WAR on K buffer)
// LDS: 2x12KB K + 4.5KB P = 28.5KB.
// ---------------------------------------------------------------------------
__global__ __launch_bounds__(256) void attn_k(const u16* __restrict__ q,
                                              const u16* __restrict__ kn,
                                              const u16* __restrict__ aB,
                                              const u16* __restrict__ vT,
                                              u16* __restrict__ o) {
  __shared__ u16 lK[2][6 * 32 * 32];   // [buf][kd][krow 0..31][32]
  __shared__ u16 lP[4][16 * 36];       // per-wave P, row stride 36
  const int hwid = blockIdx.x;
  const int lid = (hwid & 7) * 320 + (hwid >> 3);   // XCD-contiguous chunks
  const int qt = 31 - (lid & 31);                   // heavy-first within head
  const int h = (lid >> 5) % 40;
  const int b = lid / 1280;
  const int q0 = qt * 64;
  const int tid = threadIdx.x, w = tid >> 6, lane = tid & 63, r = lane & 15, quad = lane >> 4;
  const int srow = lane >> 2, sseg = (lane & 3) * 8;

  bf16x8 qf[6];
  {
    const u16* qrow = q + (((size_t)(b * 2048 + q0 + w * 16 + r)) * 40 + h) * 192;
#pragma unroll
    for (int kd = 0; kd < 6; kd++) qf[kd] = *(const bf16x8*)(qrow + kd * 32 + quad * 8);
  }
  f32x4 oa[8], oL;
#pragma unroll
  for (int f = 0; f < 8; f++) oa[f] = (f32x4){0.f, 0.f, 0.f, 0.f};
  oL = (f32x4){0.f, 0.f, 0.f, 0.f};
  float m_i[4];
#pragma unroll
  for (int t = 0; t < 4; t++) m_i[t] = -3.0e38f;
  bf16x8 ones;
#pragma unroll
  for (int e = 0; e < 8; e++) ones[e] = (short)0x3F80;   // bf16 1.0
  u16* lPw = lP[w];
  const int nkt = 2 * (qt + 1);
  // V fragment voffset (bytes), per lane; per f add f*65536, per iter add 64.
  const unsigned voff0 =
      (((unsigned)((b * 40 + h) * 128 + r)) * 2048 + (unsigned)(quad * 8)) * 2u;

  // Stage K-tile kt into buffer bufi: 3 gload_lds per wave.
  auto stage = [&](int bufi, int kt) {
    const int k0 = kt * 32;
    u16* lKb = lK[bufi];
#pragma unroll
    for (int c = w; c < 12; c += 4) {
      const int kd = c >> 1;
      const int row = (c & 1) * 16 + srow;
      const u16* g =
          (kd < 4)
              ? kn + (((size_t)(b * 2048 + k0 + row)) * 40 + h) * 128 + kd * 32 + sseg
              : aB + ((size_t)(b * 2048 + k0 + row)) * 2176 + 2048 + (kd - 4) * 32 + sseg;
      gload16(g, lKb + c * 512 + lane * 8);
    }
  };

  stage(0, 0);

  for (int kt = 0; kt < nkt; kt++) {
    const int k0 = kt * 32;
    // V(kt) -> regs (asm; FIFO position between K(kt) and K(kt+1))
    bf16x8 vf[8];
    {
      const unsigned vk = voff0 + (unsigned)(k0 * 2);
#pragma unroll
      for (int f = 0; f < 8; f++) vf[f] = gload_v(vT, vk + (unsigned)(f * 65536));
    }
    if (kt + 1 < nkt) {
      stage((kt + 1) & 1, kt + 1);
      asm volatile("s_waitcnt vmcnt(11)" ::: "memory");   // K(kt) landed
    } else {
      asm volatile("s_waitcnt vmcnt(8)" ::: "memory");
    }
    __builtin_amdgcn_s_barrier();
    __builtin_amdgcn_sched_barrier(0);
    const u16* lKb = lK[kt & 1];
    // Waves fully above the causal diagonal skip compute (wave-uniform).
    const bool active = (k0 <= q0 + w * 16 + 15);
    bf16x8 ap;
    if (active) {
      f32x4 s[2];
      s[0] = (f32x4){0.f, 0.f, 0.f, 0.f};
      s[1] = (f32x4){0.f, 0.f, 0.f, 0.f};
      __builtin_amdgcn_s_setprio(1);
#pragma unroll
      for (int kd = 0; kd < 6; kd++) {
#pragma unroll
        for (int j = 0; j < 2; j++) {
          bf16x8 bk = *(const bf16x8*)&lKb[kd * 1024 + (j * 16 + r) * 32 + quad * 8];
          s[j] = MFMA16(qf[kd], bk, s[j]);
        }
      }
      __builtin_amdgcn_s_setprio(0);
      // raw-score softmax; scale folded into exp2 arg (max commutes w/ scale)
      const float SCL2 = 0.10411754f;   // (1/sqrt(192)) * log2(e)
      const bool diag = (k0 + 31 > q0 + w * 16);
      const int kq = k0 + r - q0 - w * 16 - quad * 4;   // col - row + t-offset
      float mc[4];
#pragma unroll
      for (int t = 0; t < 4; t++) {
        float mx = -3.0e38f;
#pragma unroll
        for (int j = 0; j < 2; j++) {
          float v = s[j][t];
          if (diag && (kq + j * 16 > t)) v = -3.0e38f;
          s[j][t] = v;
          mx = fmaxf(mx, v);
        }
        mc[t] = mx;
      }
#pragma unroll
      for (int off = 1; off < 16; off <<= 1) {
#pragma unroll
        for (int t = 0; t < 4; t++) mc[t] = fmaxf(mc[t], __shfl_xor(mc[t], off, 64));
      }
      // Exact defer-max: when no row's max grew, al == 1 -- skip the rescale.
      bool grow = false;
#pragma unroll
      for (int t = 0; t < 4; t++) grow = grow || (mc[t] > m_i[t]);
      if (__any(grow)) {
#pragma unroll
        for (int t = 0; t < 4; t++) {
          const float mn = fmaxf(m_i[t], mc[t]);
          const float al = exp2f_fast((m_i[t] - mn) * SCL2);
          m_i[t] = mn;
          oL[t] *= al;
#pragma unroll
          for (int f = 0; f < 8; f++) oa[f][t] *= al;
        }
      }
#pragma unroll
      for (int t = 0; t < 4; t++) {
        const float p0 = exp2f_fast((s[0][t] - m_i[t]) * SCL2);
        const float p1 = exp2f_fast((s[1][t] - m_i[t]) * SCL2);
        const unsigned pk = cvt_pk_bf16(p0, p1);
        lPw[(quad * 4 + t) * 36 + r] = (u16)pk;
        lPw[(quad * 4 + t) * 36 + 16 + r] = (u16)(pk >> 16);
      }
      ap = *(const bf16x8*)&lPw[r * 36 + quad * 8];
    }
    // UNCONDITIONAL V wait: all paths retire the asm loads this iteration.
    if (kt + 1 < nkt) {
      asm volatile("s_waitcnt vmcnt(3)" ::: "memory");
    } else {
      asm volatile("s_waitcnt vmcnt(0)" ::: "memory");
    }
    __builtin_amdgcn_sched_barrier(0);
    if (active) {
      __builtin_amdgcn_s_setprio(1);
#pragma unroll
      for (int f = 0; f < 8; f++) oa[f] = MFMA16(ap, vf[f], oa[f]);
      oL = MFMA16(ap, ones, oL);   // row-sum column
      __builtin_amdgcn_s_setprio(0);
    }
    asm volatile("s_waitcnt lgkmcnt(0)" ::: "memory");
    __builtin_amdgcn_s_barrier();       // WAR: protect K buf from stage(kt+2)
  }
  asm volatile("s_waitcnt vmcnt(0)" ::: "memory");   // retire any stragglers
#pragma unroll
  for (int t = 0; t < 4; t++) {
    const float inv = 1.0f / oL[t];
    u16* op = o + ((size_t)(b * 2048 + q0 + w * 16 + quad * 4 + t)) * 5120 + h * 128;
#pragma unroll
    for (int f = 0; f < 8; f++) op[f * 16 + r] = f2bf(oa[f][t] * inv);
  }
}

// ---------------------------------------------------------------------------
// Workspace (peak 258,998,272 B = 247 MiB, aliased by liveness):
//   [0, 17.8M)        aB   (gemm1 -> attn)
//   [17.8M, 80.7M)    qB   (gemm2 -> attn)
//   [80.7M, 122.7M)   knop (gemm3 -> attn)
//   [122.7M, 164.6M)  vT   (gemm3 -> attn)
//   tail T=[164.6M, 259.0M) reused in phases:
//     A: xB(41.9M)@T, waT(22.3M)@T+41.9M      (until gemm1)
//     B: wqbT(23.6M)@T                        (until gemm2)
//     C: wkvT(10.5M)@T                        (until gemm3)
//     D: woT(52.4M)@T, oB(41.9M)@T+52.4M     (until gemm4)
// ---------------------------------------------------------------------------
extern "C" void kernel_launch(void* const* d_in, const int* in_sizes, int n_in,
                              void* d_out, int out_size, void* d_ws, size_t ws_size,
                              hipStream_t stream) {
  const float* x = (const float*)d_in[0];
  const float* w_a = (const float*)d_in[1];
  const float* qlw = (const float*)d_in[2];
  const float* kvlw = (const float*)d_in[3];
  const float* w_qb = (const float*)d_in[4];
  const float* w_kvb = (const float*)d_in[5];
  const float* w_o = (const float*)d_in[6];
  float* out = (float*)d_out;

  char* base = (char*)d_ws;
  u16* aB   = (u16*)(base);
  u16* qB   = (u16*)(base + 17825792ULL);
  u16* knop = (u16*)(base + 80740352ULL);
  u16* vT   = (u16*)(base + 122683392ULL);
  u16* xB   = (u16*)(base + 164626432ULL);  // phase A
  u16* waT  = (u16*)(base + 206569472ULL);  // phase A
  u16* wqbT = (u16*)(base + 164626432ULL);  // phase B
  u16* wkvT = (u16*)(base + 164626432ULL);  // phase C
  u16* woT  = (u16*)(base + 164626432ULL);  // phase D
  u16* oB   = (u16*)(base + 217055232ULL);  // phase D

  // phase A: convert x, transpose w_a
  convert_k<<<20480, 256, 0, stream>>>(x, xB, 5242880);
  transpose_k<<<dim3(5120 / 64, 2176 / 64), 256, 0, stream>>>(w_a, waT, 5120, 2112);
  // a = x @ w_a   (4096 x 2176, pad cols zero)
  gemm_bt<0><<<dim3(32, 17), 256, 0, stream>>>(xB, 5120, waT, 5120, aB, 2176, nullptr, 5120);
  // rmsnorm q_c / kv_c in place
  rmsnorm_k<<<dim3(4096, 2), 256, 0, stream>>>(aB, qlw, kvlw);
  // phase B
  transpose_k<<<dim3(1536 / 64, 7680 / 64), 256, 0, stream>>>(w_qb, wqbT, 1536, 7680);
  gemm_bt<0><<<dim3(32, 60), 256, 0, stream>>>(aB, 2176, wqbT, 1536, qB, 7680, nullptr, 1536);
  // phase C
  transpose_k<<<dim3(512 / 64, 10240 / 64), 256, 0, stream>>>(w_kvb, wkvT, 512, 10240);
  gemm_bt<1><<<dim3(32, 80), 256, 0, stream>>>(aB + 1536, 2176, wkvT, 512, knop, 0, vT, 512);
  // phase D
  transpose_k<<<dim3(5120 / 64, 5120 / 64), 256, 0, stream>>>(w_o, woT, 5120, 5120);
  // rope q_pe and k_pe in place
  rope_k<<<4096, 256, 0, stream>>>(aB, qB);
  // flash causal attention -> oB
  attn_k<<<2560, 256, 0, stream>>>(qB, knop, aB, vT, oB);
  // out = oB @ w_o  (fp32 epilogue)
  gemm_bt<2><<<dim3(32, 40), 256, 0, stream>>>(oB, 5120, woT, 5120, out, 5120, nullptr, 5120);
}

// Round 6
// 1326.577 us; speedup vs baseline: 1.1137x; 1.1137x over previous
//
#include <hip/hip_runtime.h>

typedef unsigned short u16;
typedef unsigned long long u64;
typedef __attribute__((ext_vector_type(8))) short bf16x8;
typedef __attribute__((ext_vector_type(4))) float f32x4;

__device__ __forceinline__ float bf2f(u16 u) {
  unsigned int x = ((unsigned int)u) << 16;
  return __builtin_bit_cast(float, x);
}
__device__ __forceinline__ u16 f2bf(float f) {
  unsigned int x = __builtin_bit_cast(unsigned int, f);
  x += 0x7fff + ((x >> 16) & 1);   // RNE
  return (u16)(x >> 16);
}
// 2^x via v_exp_f32 (native exp2 on gfx950).
__device__ __forceinline__ float exp2f_fast(float x) {
  return __builtin_amdgcn_exp2f(x);
}
__device__ __forceinline__ void gload16(const u16* g, u16* l) {
  __builtin_amdgcn_global_load_lds((const __attribute__((address_space(1))) void*)g,
                                   (__attribute__((address_space(3))) void*)l, 16, 0, 0);
}
__device__ __forceinline__ unsigned cvt_pk_bf16(float lo, float hi) {
  unsigned r;
  asm("v_cvt_pk_bf16_f32 %0, %1, %2" : "=v"(r) : "v"(lo), "v"(hi));
  return r;
}
#define MFMA16(a, b, c) __builtin_amdgcn_mfma_f32_16x16x32_bf16(a, b, c, 0, 0, 0)

// ---------------------------------------------------------------------------
// fp32 -> bf16 elementwise convert. grid n4/256, block 256 (n4 = n/4).
// ---------------------------------------------------------------------------
__global__ __launch_bounds__(256) void convert_k(const float* __restrict__ in,
                                                 u16* __restrict__ out, int n4) {
  const int i = blockIdx.x * 256 + threadIdx.x;
  if (i < n4) {
    float4 f = ((const float4*)in)[i];
    ushort4 v;
    v.x = f2bf(f.x); v.y = f2bf(f.y); v.z = f2bf(f.z); v.w = f2bf(f.w);
    ((ushort4*)out)[i] = v;
  }
}

// ---------------------------------------------------------------------------
// Transpose+convert: in fp32 (R x C) row-major -> out bf16 (Cpad x R) row-major;
// out rows >= C zeroed. R mult of 64, C mult of 4. grid (R/64, Cpad/64), blk 256.
// ---------------------------------------------------------------------------
__global__ __launch_bounds__(256) void transpose_k(const float* __restrict__ in,
                                                   u16* __restrict__ out,
                                                   int R, int C) {
  __shared__ u16 t[64][65];
  const int r0 = blockIdx.x * 64, c0 = blockIdx.y * 64;
  const int x = threadIdx.x & 15, y = threadIdx.x >> 4;
  if (c0 < C) {
#pragma unroll
    for (int i = 0; i < 4; i++) {
      const float* g = in + (size_t)(r0 + y + 16 * i) * C + c0 + 4 * x;
      float4 v = *(const float4*)g;
      t[y + 16 * i][4 * x + 0] = f2bf(v.x);
      t[y + 16 * i][4 * x + 1] = f2bf(v.y);
      t[y + 16 * i][4 * x + 2] = f2bf(v.z);
      t[y + 16 * i][4 * x + 3] = f2bf(v.w);
    }
    __syncthreads();
#pragma unroll
    for (int i = 0; i < 4; i++) {
      const int cc = y + 16 * i;
      ushort4 v;
      v.x = t[4 * x + 0][cc];
      v.y = t[4 * x + 1][cc];
      v.z = t[4 * x + 2][cc];
      v.w = t[4 * x + 3][cc];
      *(ushort4*)(out + (size_t)(c0 + cc) * R + r0 + 4 * x) = v;
    }
  } else {
    ushort4 z = {0, 0, 0, 0};
#pragma unroll
    for (int i = 0; i < 4; i++)
      *(ushort4*)(out + (size_t)(c0 + y + 16 * i) * R + r0 + 4 * x) = z;
  }
}

// ---------------------------------------------------------------------------
// GEMM: C(M x N) = A(M x K) * Bt(N x K)^T, bf16 in, fp32 accum.
// m97 structure: 128x128 tile, BK=32, global_load_lds(16B), 16x16x32 MFMA.
// MODE 0: bf16 row-major C, stride ldc.
// MODE 1: kv split epilogue: col n -> (h = n>>8, c = n&255);
//         c<128 -> knope[row*5120 + h*128 + c]  (bf16)
//         else  -> vT[((b*40+h)*128 + (c-128))*2048 + s]  (bf16; b=row>>11)
// MODE 2: fp32 row-major C, stride ldc.
// grid = (M/128, N/128), block 256.
// ---------------------------------------------------------------------------
template <int MODE>
__global__ __launch_bounds__(256) void gemm_bt(const u16* __restrict__ A, int lda,
                                               const u16* __restrict__ Bt, int ldb,
                                               void* __restrict__ Cp, int ldc,
                                               u16* __restrict__ C1, int K) {
  __shared__ u16 lA[128 * 32];
  __shared__ u16 lB[128 * 32];
  const int tid = threadIdx.x;
  const int m0 = blockIdx.x * 128, n0 = blockIdx.y * 128;
  const int w = tid >> 6, lane = tid & 63, r = lane & 15, quad = lane >> 4;
  const int wr = (w >> 1) * 64, wc = (w & 1) * 64;

  f32x4 acc[4][4];
#pragma unroll
  for (int i = 0; i < 4; i++)
#pragma unroll
    for (int j = 0; j < 4; j++) acc[i][j] = (f32x4){0.f, 0.f, 0.f, 0.f};

  const int r_a = tid >> 2;
  const int c_a = (tid & 3) * 8;
  const u16* gA = A + (size_t)(m0 + r_a) * lda + c_a;
  const u16* gB = Bt + (size_t)(n0 + r_a) * ldb + c_a;
  u16* lAb = lA + (tid & 192) * 8;
  u16* lBb = lB + (tid & 192) * 8;

  for (int k0 = 0; k0 < K; k0 += 32) {
    __syncthreads();
    gload16(gA + k0, lAb);
    gload16(gA + (size_t)64 * lda + k0, lAb + 2048);
    gload16(gB + k0, lBb);
    gload16(gB + (size_t)64 * ldb + k0, lBb + 2048);
    __syncthreads();
    bf16x8 af[4], bf[4];
#pragma unroll
    for (int i = 0; i < 4; i++) af[i] = *(const bf16x8*)&lA[(wr + i * 16 + r) * 32 + quad * 8];
#pragma unroll
    for (int j = 0; j < 4; j++) bf[j] = *(const bf16x8*)&lB[(wc + j * 16 + r) * 32 + quad * 8];
#pragma unroll
    for (int i = 0; i < 4; i++)
#pragma unroll
      for (int j = 0; j < 4; j++) acc[i][j] = MFMA16(af[i], bf[j], acc[i][j]);
  }

#pragma unroll
  for (int i = 0; i < 4; i++) {
#pragma unroll
    for (int j = 0; j < 4; j++) {
#pragma unroll
      for (int reg = 0; reg < 4; reg++) {
        const int row = m0 + wr + i * 16 + quad * 4 + reg;
        const int col = n0 + wc + j * 16 + r;
        const float fv = acc[i][j][reg];
        if (MODE == 0) {
          ((u16*)Cp)[(size_t)row * ldc + col] = f2bf(fv);
        } else if (MODE == 2) {
          ((float*)Cp)[(size_t)row * ldc + col] = fv;
        } else {
          const int hh = col >> 8, cc = col & 255;
          if (cc < 128) {
            ((u16*)Cp)[(size_t)row * 5120 + hh * 128 + cc] = f2bf(fv);
          } else {
            const int bb = row >> 11, ss = row & 2047;
            C1[(((size_t)(bb * 40 + hh)) * 128 + (cc - 128)) * 2048 + ss] = f2bf(fv);
          }
        }
      }
    }
  }
}

// ---------------------------------------------------------------------------
// RMSNorm in-place on aB (4096 x 2176 bf16): seg 0 = cols [0,1536) w/ q_ln_w,
// seg 1 = cols [1536,2048) w/ kv_ln_w (both fp32). grid (4096, 2), block 256.
// ---------------------------------------------------------------------------
__global__ __launch_bounds__(256) void rmsnorm_k(u16* __restrict__ a,
                                                 const float* __restrict__ qw,
                                                 const float* __restrict__ kvw) {
  const int row = blockIdx.x, seg = blockIdx.y;
  const int off = seg ? 1536 : 0;
  const int width = seg ? 512 : 1536;
  const float* wp = seg ? kvw : qw;
  u16* p = a + (size_t)row * 2176 + off;
  const int tid = threadIdx.x;
  float ss = 0.f;
  for (int i = tid; i < width; i += 256) {
    float v = bf2f(p[i]);
    ss += v * v;
  }
#pragma unroll
  for (int o = 32; o >= 1; o >>= 1) ss += __shfl_xor(ss, o, 64);
  __shared__ float red[4];
  if ((tid & 63) == 0) red[tid >> 6] = ss;
  __syncthreads();
  const float tot = red[0] + red[1] + red[2] + red[3];
  const float rs = rsqrtf(tot / (float)width + 1e-6f);
  for (int i = tid; i < width; i += 256) p[i] = f2bf(bf2f(p[i]) * rs * wp[i]);
}

// ---------------------------------------------------------------------------
// RoPE in-place: k_pe at aB[row, 2048:2112]; q_pe at qB[row, h*192+128:+192).
// grid 4096, block 256.
// ---------------------------------------------------------------------------
__global__ __launch_bounds__(256) void rope_k(u16* __restrict__ a, u16* __restrict__ q) {
  const int row = blockIdx.x;
  const int s = row & 2047;
  const int tid = threadIdx.x;
  __shared__ float cs[32], sn[32];
  if (tid < 32) {
    float inv = powf(10000.f, -(float)tid * (1.f / 32.f));
    float ang = (float)s * inv;
    cs[tid] = cosf(ang);
    sn[tid] = sinf(ang);
  }
  __syncthreads();
  if (tid < 32) {
    u16* p = a + (size_t)row * 2176 + 2048;
    float t1 = bf2f(p[tid]), t2 = bf2f(p[tid + 32]);
    p[tid] = f2bf(t1 * cs[tid] - t2 * sn[tid]);
    p[tid + 32] = f2bf(t2 * cs[tid] + t1 * sn[tid]);
  }
  for (int item = tid; item < 1280; item += 256) {
    const int hh = item >> 5, i = item & 31;
    u16* p = q + (size_t)row * 7680 + hh * 192 + 128;
    float t1 = bf2f(p[i]), t2 = bf2f(p[i + 32]);
    p[i] = f2bf(t1 * cs[i] - t2 * sn[i]);
    p[i + 32] = f2bf(t2 * cs[i] + t1 * sn[i]);
  }
}

// ---------------------------------------------------------------------------
// Flash causal attention, v6:
//  - K AND V double-buffered in LDS (5 gload_lds/wave/iter), single counted
//    vmcnt(5) per iter -> both get a FULL iteration of latency cover (fixes
//    round-5's mid-iter V stall; working set > L2 so misses must be hidden).
//  - SWAPPED QK^T: s = mfma(K, Q) (free arg swap, same LDS reads). Each lane
//    owns ONE q-row (r): row-max = 7 local fmax + 2 shfl_xor (was 16 shfl);
//    m_i is a per-lane scalar; P-exp is lane-local; rescale al = 1 exp2/lane,
//    broadcast to oa rows by 4 bpermutes only when the max grows.
//  - P LDS stride 40 u16: u64 writes / b128 reads both 16B-aligned and
//    bank-uniform (8/bank floor, no conflicts).
//  - Row-sum l via ones-MFMA; scale folded into exp2 arg; cvt_pk packing.
// LDS: 2x12KB K + 2x8KB V + 5KB P = 45.1KB -> 3 blocks/CU.
// Per iter: stage(kt+1):5 -> vmcnt(5) [K,V(kt) landed] -> barrier -> compute
//           -> lgkmcnt(0) -> barrier (WAR).
// ---------------------------------------------------------------------------
__global__ __launch_bounds__(256) void attn_k(const u16* __restrict__ q,
                                              const u16* __restrict__ kn,
                                              const u16* __restrict__ aB,
                                              const u16* __restrict__ vT,
                                              u16* __restrict__ o) {
  __shared__ u16 lK[2][6 * 32 * 32];   // [buf][kd][krow 0..31][32]
  __shared__ u16 lV[2][128 * 32];      // [buf][dvrow 0..127][32]
  __shared__ u16 lP[4][16 * 40];       // per-wave P, row stride 40
  const int hwid = blockIdx.x;
  const int lid = (hwid & 7) * 320 + (hwid >> 3);   // XCD-contiguous chunks
  const int qt = 31 - (lid & 31);                   // heavy-first within head
  const int h = (lid >> 5) % 40;
  const int b = lid / 1280;
  const int q0 = qt * 64;
  const int tid = threadIdx.x, w = tid >> 6, lane = tid & 63, r = lane & 15, quad = lane >> 4;
  const int srow = lane >> 2, sseg = (lane & 3) * 8;

  bf16x8 qf[6];
  {
    const u16* qrow = q + (((size_t)(b * 2048 + q0 + w * 16 + r)) * 40 + h) * 192;
#pragma unroll
    for (int kd = 0; kd < 6; kd++) qf[kd] = *(const bf16x8*)(qrow + kd * 32 + quad * 8);
  }
  f32x4 oa[8], oL;
#pragma unroll
  for (int f = 0; f < 8; f++) oa[f] = (f32x4){0.f, 0.f, 0.f, 0.f};
  oL = (f32x4){0.f, 0.f, 0.f, 0.f};
  float m_i = -3.0e38f;   // per-lane: running max of q-row (q0 + w*16 + r)
  bf16x8 ones;
#pragma unroll
  for (int e = 0; e < 8; e++) ones[e] = (short)0x3F80;   // bf16 1.0
  u16* lPw = lP[w];
  const int nkt = 2 * (qt + 1);

  // Stage K+V tile kt into buffer bufi: 3 K + 2 V gload_lds per wave.
  auto stage = [&](int bufi, int kt) {
    const int k0 = kt * 32;
    u16* lKb = lK[bufi];
    u16* lVb = lV[bufi];
#pragma unroll
    for (int c = w; c < 12; c += 4) {
      const int kd = c >> 1;
      const int row = (c & 1) * 16 + srow;
      const u16* g =
          (kd < 4)
              ? kn + (((size_t)(b * 2048 + k0 + row)) * 40 + h) * 128 + kd * 32 + sseg
              : aB + ((size_t)(b * 2048 + k0 + row)) * 2176 + 2048 + (kd - 4) * 32 + sseg;
      gload16(g, lKb + c * 512 + lane * 8);
    }
#pragma unroll
    for (int c = w; c < 8; c += 4) {
      const u16* g = vT + (((size_t)(b * 40 + h)) * 128 + c * 16 + srow) * 2048 + k0 + sseg;
      gload16(g, lVb + c * 512 + lane * 8);
    }
  };

  stage(0, 0);

  for (int kt = 0; kt < nkt; kt++) {
    const int k0 = kt * 32;
    if (kt + 1 < nkt) {
      stage((kt + 1) & 1, kt + 1);
      asm volatile("s_waitcnt vmcnt(5)" ::: "memory");   // tile kt fully landed
    } else {
      asm volatile("s_waitcnt vmcnt(0)" ::: "memory");
    }
    __builtin_amdgcn_s_barrier();
    __builtin_amdgcn_sched_barrier(0);
    const u16* lKb = lK[kt & 1];
    const u16* lVb = lV[kt & 1];
    // Waves fully above the causal diagonal skip compute (wave-uniform).
    if (k0 <= q0 + w * 16 + 15) {
      // QK^T, SWAPPED: A = K rows, B = Q rows -> lane holds q-row r,
      // k = k0 + j*16 + quad*4 + t.
      f32x4 s[2];
      s[0] = (f32x4){0.f, 0.f, 0.f, 0.f};
      s[1] = (f32x4){0.f, 0.f, 0.f, 0.f};
      __builtin_amdgcn_s_setprio(1);
#pragma unroll
      for (int kd = 0; kd < 6; kd++) {
#pragma unroll
        for (int j = 0; j < 2; j++) {
          bf16x8 bk = *(const bf16x8*)&lKb[kd * 1024 + (j * 16 + r) * 32 + quad * 8];
          s[j] = MFMA16(bk, qf[kd], s[j]);
        }
      }
      __builtin_amdgcn_s_setprio(0);
      const float SCL2 = 0.10411754f;   // (1/sqrt(192)) * log2(e)
      const bool diag = (k0 + 31 > q0 + w * 16);
      const int dlt = q0 + w * 16 + r - k0 - quad * 4;   // mask iff j*16+t > dlt
      float mx = -3.0e38f;
#pragma unroll
      for (int j = 0; j < 2; j++) {
#pragma unroll
        for (int t = 0; t < 4; t++) {
          float v = s[j][t];
          if (diag && (j * 16 + t > dlt)) v = -3.0e38f;
          s[j][t] = v;
          mx = fmaxf(mx, v);
        }
      }
      // cross-quad row max (2 stages; lanes with same r share a q-row)
      mx = fmaxf(mx, __shfl_xor(mx, 16, 64));
      mx = fmaxf(mx, __shfl_xor(mx, 32, 64));
      // Exact defer-max: rescale only when some row's max grew (al==1 else).
      if (__any(mx > m_i)) {
        const float mn = fmaxf(m_i, mx);
        const float al = exp2f_fast((m_i - mn) * SCL2);
        m_i = mn;
        // broadcast al of q-row (quad*4+t) from lane (quad*4+t) to oa rows
#pragma unroll
        for (int t = 0; t < 4; t++) {
          const float alb = __shfl(al, quad * 4 + t, 64);
          oL[t] *= alb;
#pragma unroll
          for (int f = 0; f < 8; f++) oa[f][t] *= alb;
        }
      }
      // P = exp2((s - m)*SCL2), lane-local; pack and store one u64 per j.
#pragma unroll
      for (int j = 0; j < 2; j++) {
        const unsigned lo = cvt_pk_bf16(exp2f_fast((s[j][0] - m_i) * SCL2),
                                        exp2f_fast((s[j][1] - m_i) * SCL2));
        const unsigned hi = cvt_pk_bf16(exp2f_fast((s[j][2] - m_i) * SCL2),
                                        exp2f_fast((s[j][3] - m_i) * SCL2));
        *(u64*)&lPw[r * 40 + j * 16 + quad * 4] = ((u64)hi << 32) | lo;
      }
      bf16x8 ap = *(const bf16x8*)&lPw[r * 40 + quad * 8];
      __builtin_amdgcn_s_setprio(1);
#pragma unroll
      for (int f = 0; f < 8; f++) {
        bf16x8 bv = *(const bf16x8*)&lVb[(f * 16 + r) * 32 + quad * 8];
        oa[f] = MFMA16(ap, bv, oa[f]);
      }
      oL = MFMA16(ap, ones, oL);   // row-sum column
      __builtin_amdgcn_s_setprio(0);
    }
    asm volatile("s_waitcnt lgkmcnt(0)" ::: "memory");
    __builtin_amdgcn_s_barrier();       // WAR: protect bufs from stage(kt+2)
  }
#pragma unroll
  for (int t = 0; t < 4; t++) {
    const float inv = 1.0f / oL[t];
    u16* op = o + ((size_t)(b * 2048 + q0 + w * 16 + quad * 4 + t)) * 5120 + h * 128;
#pragma unroll
    for (int f = 0; f < 8; f++) op[f * 16 + r] = f2bf(oa[f][t] * inv);
  }
}

// ---------------------------------------------------------------------------
// Workspace (peak 258,998,272 B = 247 MiB, aliased by liveness):
//   [0, 17.8M)        aB   (gemm1 -> attn)
//   [17.8M, 80.7M)    qB   (gemm2 -> attn)
//   [80.7M, 122.7M)   knop (gemm3 -> attn)
//   [122.7M, 164.6M)  vT   (gemm3 -> attn)
//   tail T=[164.6M, 259.0M) reused in phases:
//     A: xB(41.9M)@T, waT(22.3M)@T+41.9M      (until gemm1)
//     B: wqbT(23.6M)@T                        (until gemm2)
//     C: wkvT(10.5M)@T                        (until gemm3)
//     D: woT(52.4M)@T, oB(41.9M)@T+52.4M     (until gemm4)
// ---------------------------------------------------------------------------
extern "C" void kernel_launch(void* const* d_in, const int* in_sizes, int n_in,
                              void* d_out, int out_size, void* d_ws, size_t ws_size,
                              hipStream_t stream) {
  const float* x = (const float*)d_in[0];
  const float* w_a = (const float*)d_in[1];
  const float* qlw = (const float*)d_in[2];
  const float* kvlw = (const float*)d_in[3];
  const float* w_qb = (const float*)d_in[4];
  const float* w_kvb = (const float*)d_in[5];
  const float* w_o = (const float*)d_in[6];
  float* out = (float*)d_out;

  char* base = (char*)d_ws;
  u16* aB   = (u16*)(base);
  u16* qB   = (u16*)(base + 17825792ULL);
  u16* knop = (u16*)(base + 80740352ULL);
  u16* vT   = (u16*)(base + 122683392ULL);
  u16* xB   = (u16*)(base + 164626432ULL);  // phase A
  u16* waT  = (u16*)(base + 206569472ULL);  // phase A
  u16* wqbT = (u16*)(base + 164626432ULL);  // phase B
  u16* wkvT = (u16*)(base + 164626432ULL);  // phase C
  u16* woT  = (u16*)(base + 164626432ULL);  // phase D
  u16* oB   = (u16*)(base + 217055232ULL);  // phase D

  // phase A: convert x, transpose w_a
  convert_k<<<20480, 256, 0, stream>>>(x, xB, 5242880);
  transpose_k<<<dim3(5120 / 64, 2176 / 64), 256, 0, stream>>>(w_a, waT, 5120, 2112);
  // a = x @ w_a   (4096 x 2176, pad cols zero)
  gemm_bt<0><<<dim3(32, 17), 256, 0, stream>>>(xB, 5120, waT, 5120, aB, 2176, nullptr, 5120);
  // rmsnorm q_c / kv_c in place
  rmsnorm_k<<<dim3(4096, 2), 256, 0, stream>>>(aB, qlw, kvlw);
  // phase B
  transpose_k<<<dim3(1536 / 64, 7680 / 64), 256, 0, stream>>>(w_qb, wqbT, 1536, 7680);
  gemm_bt<0><<<dim3(32, 60), 256, 0, stream>>>(aB, 2176, wqbT, 1536, qB, 7680, nullptr, 1536);
  // phase C
  transpose_k<<<dim3(512 / 64, 10240 / 64), 256, 0, stream>>>(w_kvb, wkvT, 512, 10240);
  gemm_bt<1><<<dim3(32, 80), 256, 0, stream>>>(aB + 1536, 2176, wkvT, 512, knop, 0, vT, 512);
  // phase D
  transpose_k<<<dim3(5120 / 64, 5120 / 64), 256, 0, stream>>>(w_o, woT, 5120, 5120);
  // rope q_pe and k_pe in place
  rope_k<<<4096, 256, 0, stream>>>(aB, qB);
  // flash causal attention -> oB
  attn_k<<<2560, 256, 0, stream>>>(qB, knop, aB, vT, oB);
  // out = oB @ w_o  (fp32 epilogue)
  gemm_bt<2><<<dim3(32, 40), 256, 0, stream>>>(oB, 5120, woT, 5120, out, 5120, nullptr, 5120);
}